// Round 1
// baseline (443.387 us; speedup 1.0000x reference)
//
#include <hip/hip_runtime.h>

constexpr int BOND = 64;
constexpr int RANK = 16;
constexpr int BT   = 8;    // batch tile per block
constexpr int O48  = 48;   // OUT_C * PATCH * PATCH
constexpr int NTHR = 256;

// factor row offsets per level: (4^L - 1) / 3
// L0:0  L1:1  L2:5  L3:21  L4:85  L5:341

__device__ __forceinline__ void node_lat(const float* __restrict__ f_in,
                                         const float* __restrict__ scale,
                                         int fo,
                                         const float* xin,   // LDS [BT][64]
                                         float* lat,         // LDS [BT][16]
                                         int tid)
{
    // 256 threads: b = tid>>5 (8), r = (tid>>1)&15, h = tid&1 (half of dot)
    const int b = tid >> 5;
    const int r = (tid >> 1) & 15;
    const int h = tid & 1;
    const float* fir = f_in + (size_t)fo * (RANK * BOND) + r * BOND + h * 32;
    const float* xb  = xin + b * BOND + h * 32;
    float p = 0.f;
#pragma unroll
    for (int i = 0; i < 32; ++i) p += fir[i] * xb[i];
    p += __shfl_xor(p, 1);
    if (h == 0) lat[b * RANK + r] = p * scale[(size_t)fo * RANK + r];
}

__device__ __forceinline__ void node_children(const float* __restrict__ fd, // global, [16][64] at node
                                              const float* xin,  // LDS [BT][64]
                                              const float* lat,  // LDS [BT][16]
                                              float* xout,       // LDS [BT][64]
                                              int tid)
{
    // 256 threads: o = tid&63, b0 = tid>>6 (0..3), loop bi += 4
    const int o  = tid & 63;
    const int b0 = tid >> 6;
    float f[RANK];
#pragma unroll
    for (int r = 0; r < RANK; ++r) f[r] = fd[r * BOND + o];
#pragma unroll
    for (int bi = 0; bi < BT; bi += 4) {
        const int b = b0 + bi;
        float acc = xin[b * BOND + o];
#pragma unroll
        for (int r = 0; r < RANK; ++r) acc += lat[b * RANK + r] * f[r];
        xout[b * BOND + o] = acc;
    }
}

__global__ __launch_bounds__(NTHR, 2)
void qtree_kernel(const float* __restrict__ x,      // [128][1][64]
                  const float* __restrict__ f_in,   // [1365][16][64]
                  const float* __restrict__ f_tl,
                  const float* __restrict__ f_tr,
                  const float* __restrict__ f_bl,
                  const float* __restrict__ f_br,
                  const float* __restrict__ scale,  // [1365][16]
                  const float* __restrict__ head_w, // [48][64]
                  const float* __restrict__ head_b, // [48]
                  float* __restrict__ out)          // [128][3][256][256]
{
    __shared__ float s_x4[4][BT][BOND];     // level-4 inputs      (8 KB)
    __shared__ float s_x5[16][BT][BOND];    // level-5 inputs      (32 KB)
    __shared__ float s_tmp[4][BT][BOND];    // path ping-pong / leaf buffer (8 KB)
    __shared__ float s_lat[BT][RANK];
    __shared__ float s_hw[O48][BOND + 1];   // +1 pad: unpadded -> 64-way bank conflict in head loop
    __shared__ float s_hb[O48];

    const int tid = threadIdx.x;
    const int n3  = blockIdx.x;   // 0..63  (level-3 node, y3*8+x3)
    const int bg  = blockIdx.y;   // 0..15  (batch group)
    const int y3  = n3 >> 3, x3 = n3 & 7;

    const float* fdir[4] = { f_tl, f_tr, f_bl, f_br };

    // stage head weights/bias
    for (int i = tid; i < O48 * BOND; i += NTHR) s_hw[i / BOND][i % BOND] = head_w[i];
    if (tid < O48) s_hb[tid] = head_b[tid];

    // load x for this batch group into s_tmp[0]
    for (int i = tid; i < BT * BOND; i += NTHR) {
        const int b = i / BOND, o = i % BOND;
        s_tmp[0][b][o] = x[(size_t)(bg * BT + b) * BOND + o];
    }
    __syncthreads();

    // ---- ancestor path: levels 0,1,2 (single child each) ----
    {   // L0: node 0, child = (y3>>2, x3>>2)
        const int fo = 0;
        const int d  = ((y3 >> 2) << 1) | (x3 >> 2);
        node_lat(f_in, scale, fo, &s_tmp[0][0][0], &s_lat[0][0], tid);
        __syncthreads();
        node_children(fdir[d] + (size_t)fo * RANK * BOND, &s_tmp[0][0][0], &s_lat[0][0], &s_tmp[1][0][0], tid);
        __syncthreads();
    }
    {   // L1: node (y3>>2, x3>>2) on 2x2, child = ((y3>>1)&1, (x3>>1)&1)
        const int fo = 1 + ((y3 >> 2) * 2 + (x3 >> 2));
        const int d  = (((y3 >> 1) & 1) << 1) | ((x3 >> 1) & 1);
        node_lat(f_in, scale, fo, &s_tmp[1][0][0], &s_lat[0][0], tid);
        __syncthreads();
        node_children(fdir[d] + (size_t)fo * RANK * BOND, &s_tmp[1][0][0], &s_lat[0][0], &s_tmp[2][0][0], tid);
        __syncthreads();
    }
    {   // L2: node (y3>>1, x3>>1) on 4x4, child = (y3&1, x3&1)
        const int fo = 5 + ((y3 >> 1) * 4 + (x3 >> 1));
        const int d  = ((y3 & 1) << 1) | (x3 & 1);
        node_lat(f_in, scale, fo, &s_tmp[2][0][0], &s_lat[0][0], tid);
        __syncthreads();
        node_children(fdir[d] + (size_t)fo * RANK * BOND, &s_tmp[2][0][0], &s_lat[0][0], &s_tmp[3][0][0], tid);
        __syncthreads();
    }

    // ---- L3: this block's node, 4 children -> s_x4 ----
    {
        const int fo = 21 + n3;
        node_lat(f_in, scale, fo, &s_tmp[3][0][0], &s_lat[0][0], tid);
        __syncthreads();
#pragma unroll
        for (int d = 0; d < 4; ++d)
            node_children(fdir[d] + (size_t)fo * RANK * BOND, &s_tmp[3][0][0], &s_lat[0][0], &s_x4[d][0][0], tid);
        __syncthreads();
    }

    // ---- L4: 4 nodes -> s_x5 (indexed by (u,v) in 4x4 local grid) ----
    for (int j = 0; j < 4; ++j) {
        const int jy = j >> 1, jx = j & 1;
        const int fo = 85 + (((y3 << 1) + jy) * 16 + ((x3 << 1) + jx));
        node_lat(f_in, scale, fo, &s_x4[j][0][0], &s_lat[0][0], tid);
        __syncthreads();
#pragma unroll
        for (int d = 0; d < 4; ++d) {
            const int dy = d >> 1, dx = d & 1;
            const int slot = ((jy << 1) + dy) * 4 + ((jx << 1) + dx);
            node_children(fdir[d] + (size_t)fo * RANK * BOND, &s_x4[j][0][0], &s_lat[0][0], &s_x5[slot][0][0], tid);
        }
        __syncthreads();
    }

    // ---- L5: 16 nodes; children -> s_tmp (leaf buffer) -> fused head -> out ----
    for (int k = 0; k < 16; ++k) {
        const int u = k >> 2, v = k & 3;
        const int y5 = (y3 << 2) + u, x5 = (x3 << 2) + v;
        const int fo = 341 + (y5 * 32 + x5);
        node_lat(f_in, scale, fo, &s_x5[k][0][0], &s_lat[0][0], tid);
        __syncthreads();
#pragma unroll
        for (int d = 0; d < 4; ++d)
            node_children(fdir[d] + (size_t)fo * RANK * BOND, &s_x5[k][0][0], &s_lat[0][0], &s_tmp[d][0][0], tid);
        __syncthreads();

        // head on the 4*BT leaves in s_tmp; scatter to output image
        const int Yb = y5 << 1, Xb = x5 << 1;
        for (int idx = tid; idx < 4 * BT * O48; idx += NTHR) {
            const int d   = idx / (BT * O48);
            const int rem = idx - d * (BT * O48);
            const int b   = rem / O48;
            const int o   = rem - b * O48;
            const float* lf = &s_tmp[d][b][0];
            float acc = s_hb[o];
#pragma unroll
            for (int i = 0; i < BOND; ++i) acc += lf[i] * s_hw[o][i];
            const int cy = d >> 1, cx = d & 1;
            const int Y = Yb + cy, X = Xb + cx;
            const int py = o / 12;
            const int px = (o / 3) & 3;
            const int ch = o - (o / 3) * 3;
            const size_t oidx = ((((size_t)(bg * BT + b) * 3 + ch) * 256) + (Y * 4 + py)) * 256 + (X * 4 + px);
            out[oidx] = acc;
        }
        __syncthreads();
    }
}

extern "C" void kernel_launch(void* const* d_in, const int* in_sizes, int n_in,
                              void* d_out, int out_size, void* d_ws, size_t ws_size,
                              hipStream_t stream) {
    const float* x    = (const float*)d_in[0];
    const float* f_in = (const float*)d_in[1];
    const float* f_tl = (const float*)d_in[2];
    const float* f_tr = (const float*)d_in[3];
    const float* f_bl = (const float*)d_in[4];
    const float* f_br = (const float*)d_in[5];
    const float* sc   = (const float*)d_in[6];
    const float* hw   = (const float*)d_in[7];
    const float* hb   = (const float*)d_in[8];
    float* out = (float*)d_out;

    dim3 grid(64, 16);   // 64 level-3 nodes x 16 batch groups
    qtree_kernel<<<grid, NTHR, 0, stream>>>(x, f_in, f_tl, f_tr, f_bl, f_br, sc, hw, hb, out);
}

// Round 2
// 340.930 us; speedup vs baseline: 1.3005x; 1.3005x over previous
//
#include <hip/hip_runtime.h>

constexpr int BOND = 64;
constexpr int RANK = 16;
constexpr int BT   = 8;    // batch tile per block
constexpr int O48  = 48;   // OUT_C * PATCH * PATCH
constexpr int NTHR = 256;
constexpr int LPAD = 68;   // leaf row stride (floats): 272 B = 16B-aligned, 2-way max conflicts
constexpr int HPAD = 68;   // head_w row stride (floats)

// factor row offsets per level: L0:0  L1:1  L2:5  L3:21  L4:85  L5:341

__device__ __forceinline__ void node_lat(const float* __restrict__ f_in,
                                         const float* __restrict__ scale,
                                         int fo,
                                         const float* xin,   // LDS [BT][64]
                                         float* lat,         // LDS [BT][16]
                                         int tid)
{
    // 256 threads: b = tid>>5 (8), r = (tid>>1)&15, h = tid&1 (half of dot)
    const int b = tid >> 5;
    const int r = (tid >> 1) & 15;
    const int h = tid & 1;
    const float4* fir = (const float4*)(f_in + (size_t)fo * (RANK * BOND) + r * BOND + h * 32);
    const float4* xb  = (const float4*)(xin + b * BOND + h * 32);
    float p = 0.f;
#pragma unroll
    for (int i = 0; i < 8; ++i) {
        const float4 a = fir[i], c = xb[i];
        p += a.x * c.x + a.y * c.y + a.z * c.z + a.w * c.w;
    }
    p += __shfl_xor(p, 1);
    if (h == 0) lat[b * RANK + r] = p * scale[fo * RANK + r];
}

__device__ __forceinline__ void node_children(const float* __restrict__ fd, // global [16][64] at node
                                              const float* xin,   // LDS [BT][64]
                                              const float* lat,   // LDS [BT][16]
                                              float* xout,        // LDS, row b at xout[b*bstride]
                                              int bstride,
                                              int tid)
{
    const int o  = tid & 63;
    const int b0 = tid >> 6;
    float f[RANK];
#pragma unroll
    for (int r = 0; r < RANK; ++r) f[r] = fd[r * BOND + o];
#pragma unroll
    for (int bi = 0; bi < BT; bi += 4) {
        const int b = b0 + bi;
        float acc = xin[b * BOND + o];
#pragma unroll
        for (int r = 0; r < RANK; ++r) acc += lat[b * RANK + r] * f[r];
        xout[b * bstride + o] = acc;
    }
}

__global__ __launch_bounds__(NTHR, 3)
void qtree_kernel(const float* __restrict__ x,      // [128][1][64]
                  const float* __restrict__ f_in,   // [1365][16][64]
                  const float* __restrict__ f_tl,
                  const float* __restrict__ f_tr,
                  const float* __restrict__ f_bl,
                  const float* __restrict__ f_br,
                  const float* __restrict__ scale,  // [1365][16]
                  const float* __restrict__ head_w, // [48][64]
                  const float* __restrict__ head_b, // [48]
                  float* __restrict__ out)          // [128][3][256][256]
{
    __shared__ float s_x4[2][BT][BOND];       // 4 KB: this block's 2 L4 subtree inputs
    __shared__ float s_x5[4][BT][BOND];       // 8 KB: path ping-pong, then L5 inputs
    __shared__ float s_leafy[64 * LPAD];      // 17.4 KB: leaf buffer, aliased as s_y[8][3][8][16]
    __shared__ float s_hw[O48][HPAD];         // 13 KB
    __shared__ float s_hb[O48];
    __shared__ float s_lat[4][BT][RANK];      // 2 KB
    // total ~44 KB -> 3 blocks/CU

    const int tid = threadIdx.x;
    const int n3  = blockIdx.x;   // 0..63  level-3 node (y3*8+x3)
    const int bg  = blockIdx.y;   // 0..15  batch group
    const int jy  = blockIdx.z;   // 0..1   which L4 row-half of the subtree
    const int y3  = n3 >> 3, x3 = n3 & 7;

    const float* fdir[4] = { f_tl, f_tr, f_bl, f_br };

    // stage head weights (padded) + bias
    for (int i4 = tid; i4 < O48 * BOND / 4; i4 += NTHR) {  // 768 float4
        const int r = i4 >> 4, c4 = i4 & 15;
        *(float4*)&s_hw[r][c4 * 4] = ((const float4*)head_w)[i4];
    }
    if (tid < O48) s_hb[tid] = head_b[tid];

    // load x for this batch group into s_x5[0]
    for (int i4 = tid; i4 < BT * BOND / 4; i4 += NTHR)     // 128 float4
        ((float4*)&s_x5[0][0][0])[i4] = ((const float4*)(x + (size_t)bg * BT * BOND))[i4];
    __syncthreads();

    // ---- ancestor path L0 -> L1 -> L2 (single child each), buffers s_x5[0..3] ----
    {   // L0
        node_lat(f_in, scale, 0, &s_x5[0][0][0], &s_lat[0][0][0], tid);
        __syncthreads();
        const int d = ((y3 >> 2) << 1) | (x3 >> 2);
        node_children(fdir[d], &s_x5[0][0][0], &s_lat[0][0][0], &s_x5[1][0][0], BOND, tid);
        __syncthreads();
    }
    {   // L1
        const int fo = 1 + ((y3 >> 2) * 2 + (x3 >> 2));
        node_lat(f_in, scale, fo, &s_x5[1][0][0], &s_lat[0][0][0], tid);
        __syncthreads();
        const int d = (((y3 >> 1) & 1) << 1) | ((x3 >> 1) & 1);
        node_children(fdir[d] + (size_t)fo * RANK * BOND, &s_x5[1][0][0], &s_lat[0][0][0], &s_x5[2][0][0], BOND, tid);
        __syncthreads();
    }
    {   // L2
        const int fo = 5 + ((y3 >> 1) * 4 + (x3 >> 1));
        node_lat(f_in, scale, fo, &s_x5[2][0][0], &s_lat[0][0][0], tid);
        __syncthreads();
        const int d = ((y3 & 1) << 1) | (x3 & 1);
        node_children(fdir[d] + (size_t)fo * RANK * BOND, &s_x5[2][0][0], &s_lat[0][0][0], &s_x5[3][0][0], BOND, tid);
        __syncthreads();
    }
    // ---- L3: children only for d = 2*jy + jx -> s_x4[jx] ----
    {
        const int fo = 21 + n3;
        node_lat(f_in, scale, fo, &s_x5[3][0][0], &s_lat[0][0][0], tid);
        __syncthreads();
#pragma unroll
        for (int jx = 0; jx < 2; ++jx)
            node_children(fdir[2 * jy + jx] + (size_t)fo * RANK * BOND,
                          &s_x5[3][0][0], &s_lat[0][0][0], &s_x4[jx][0][0], BOND, tid);
        __syncthreads();
    }

    // ---- two L4 subtrees, depth-first ----
    for (int jx = 0; jx < 2; ++jx) {
        const int y4 = 2 * y3 + jy, x4c = 2 * x3 + jx;
        const int fo4 = 85 + y4 * 16 + x4c;
        node_lat(f_in, scale, fo4, &s_x4[jx][0][0], &s_lat[0][0][0], tid);
        __syncthreads();
#pragma unroll
        for (int e = 0; e < 4; ++e)
            node_children(fdir[e] + (size_t)fo4 * RANK * BOND,
                          &s_x4[jx][0][0], &s_lat[0][0][0], &s_x5[e][0][0], BOND, tid);
        __syncthreads();

        // L5 lats for the 4 nodes (no barrier between: disjoint outputs)
        int fo5[4];
#pragma unroll
        for (int e = 0; e < 4; ++e) {
            const int dy = e >> 1, dx = e & 1;
            fo5[e] = 341 + (2 * y4 + dy) * 32 + (2 * x4c + dx);
            node_lat(f_in, scale, fo5[e], &s_x5[e][0][0], &s_lat[e][0][0], tid);
        }
        __syncthreads();

        // ---- two head passes per subtree (p = dy half) ----
        for (int p = 0; p < 2; ++p) {
            // children for e = 2p+dx2: leaves l = b*8 + dx2*4 + c
#pragma unroll
            for (int dx2 = 0; dx2 < 2; ++dx2) {
                const int e = 2 * p + dx2;
#pragma unroll
                for (int c = 0; c < 4; ++c)
                    node_children(fdir[c] + (size_t)fo5[e] * RANK * BOND,
                                  &s_x5[e][0][0], &s_lat[e][0][0],
                                  s_leafy + (dx2 * 4 + c) * LPAD, 8 * LPAD, tid);
            }
            __syncthreads();

            // head: register tile 4 leaves x 3 outputs per thread
            const int lgrp = tid >> 4;   // 0..15 -> leaves lgrp*4 .. +3
            const int ogrp = tid & 15;   // 0..15 -> o = ogrp*3 .. +2
            float acc[4][3];
#pragma unroll
            for (int q = 0; q < 4; ++q)
#pragma unroll
                for (int t = 0; t < 3; ++t) acc[q][t] = s_hb[ogrp * 3 + t];
#pragma unroll
            for (int i4 = 0; i4 < 16; ++i4) {
                float4 lf[4], hw[3];
#pragma unroll
                for (int q = 0; q < 4; ++q) lf[q] = *(const float4*)&s_leafy[(lgrp * 4 + q) * LPAD + i4 * 4];
#pragma unroll
                for (int t = 0; t < 3; ++t) hw[t] = *(const float4*)&s_hw[ogrp * 3 + t][i4 * 4];
#pragma unroll
                for (int q = 0; q < 4; ++q)
#pragma unroll
                    for (int t = 0; t < 3; ++t)
                        acc[q][t] += lf[q].x * hw[t].x + lf[q].y * hw[t].y
                                   + lf[q].z * hw[t].z + lf[q].w * hw[t].w;
            }
            __syncthreads();

            // stage y in LDS (alias s_leafy): [b][ch][r2][c2] = [8][3][8][16]
            float* s_y = s_leafy;
#pragma unroll
            for (int q = 0; q < 4; ++q) {
                const int l = lgrp * 4 + q;
                const int b = l >> 3, dx = (l >> 2) & 1, c = l & 3;
                const int cy = c >> 1, cx = c & 1;
#pragma unroll
                for (int t = 0; t < 3; ++t) {
                    const int o  = ogrp * 3 + t;
                    const int py = o / 12, px = (o / 3) & 3, ch = o % 3;
                    s_y[((b * 3 + ch) * 8 + (cy * 4 + py)) * 16 + (dx * 8 + cx * 4 + px)] = acc[q][t];
                }
            }
            __syncthreads();

            // coalesced 64B-aligned stores: rows of 16 floats
            const int base_row = (4 * y3 + 2 * jy + p) * 8;
            const int base_col = (4 * x3 + 2 * jx) * 8;
#pragma unroll
            for (int s = 0; s < 3; ++s) {
                const int idx = tid + NTHR * s;    // 0..767 float4 chunks
                const int c4  = idx & 3;
                const int r2  = (idx >> 2) & 7;
                const int bc  = idx >> 5;          // b*3+ch, 0..23
                const float4 v = *(const float4*)&s_y[(bc * 8 + r2) * 16 + c4 * 4];
                const size_t off = ((size_t)(bg * BT + bc / 3) * 3 + (bc % 3)) * 65536
                                 + (size_t)(base_row + r2) * 256 + base_col + c4 * 4;
                *(float4*)&out[off] = v;
            }
            __syncthreads();
        } // p
    } // jx
}

extern "C" void kernel_launch(void* const* d_in, const int* in_sizes, int n_in,
                              void* d_out, int out_size, void* d_ws, size_t ws_size,
                              hipStream_t stream) {
    const float* x    = (const float*)d_in[0];
    const float* f_in = (const float*)d_in[1];
    const float* f_tl = (const float*)d_in[2];
    const float* f_tr = (const float*)d_in[3];
    const float* f_bl = (const float*)d_in[4];
    const float* f_br = (const float*)d_in[5];
    const float* sc   = (const float*)d_in[6];
    const float* hw   = (const float*)d_in[7];
    const float* hb   = (const float*)d_in[8];
    float* out = (float*)d_out;

    dim3 grid(64, 16, 2);   // L3 node x batch-group x jy-half
    qtree_kernel<<<grid, NTHR, 0, stream>>>(x, f_in, f_tl, f_tr, f_bl, f_br, sc, hw, hb, out);
}